// Round 8
// baseline (5561.324 us; speedup 1.0000x reference)
//
#include <hip/hip_runtime.h>
#include <math.h>

// Fused LFADS DecoderCell, fp32 vector-FMA version.
// B=32768 independent rows; each block owns BM=32 rows through the whole chain:
//   con-GRU(384->256) -> co(256->128)+reparam -> gen-GRU(80->512) -> factor(512->128)
// h_0 layout: [gen 0:512 | con 512:768 | mean 768:832 | std 832:896 | gin 896:976 | fac 976:1104]

#define IN_LD   272
#define H0_LD   1104
#define OUT_LD  1104
#define CLIP_V  5.0f

__device__ __forceinline__ void fma4(float& acc, const float4 a, const float4 b) {
    acc = fmaf(a.x, b.x, acc);
    acc = fmaf(a.y, b.y, acc);
    acc = fmaf(a.z, b.z, acc);
    acc = fmaf(a.w, b.w, acc);
}

__device__ __forceinline__ float sigm(float x) { return 1.0f / (1.0f + expf(-x)); }

// ---------------- fac_w row norms (128 rows x 512) -> d_ws ----------------
__global__ void fac_norm_kernel(const float* __restrict__ fac_w,
                                float* __restrict__ norms) {
    const int j = blockIdx.x;      // 0..127
    const int l = threadIdx.x;     // 0..63
    float s = 0.f;
#pragma unroll
    for (int k = 0; k < 8; ++k) {
        const float v = fac_w[j * 512 + l + 64 * k];
        s = fmaf(v, v, s);
    }
#pragma unroll
    for (int off = 32; off > 0; off >>= 1) s += __shfl_xor(s, off);
    if (l == 0) norms[j] = fmaxf(sqrtf(s), 1e-12f);
}

// cooperative 32 x COLS tile load into an LDS buffer of row stride 512
template<int COLS>
__device__ __forceinline__ void load_tile(float* __restrict__ dst, int dst_col0,
                                          const float* __restrict__ src, int src_ld) {
    constexpr int C4 = COLS / 4;
    constexpr int TOT = 32 * C4;
    for (int idx = threadIdx.x; idx < TOT; idx += 512) {
        const int r = idx / C4;
        const int c = idx - r * C4;
        const float4 v = *(const float4*)(src + (size_t)r * src_ld + c * 4);
        *(float4*)(dst + r * 512 + dst_col0 + c * 4) = v;
    }
}

__global__ __launch_bounds__(512, 2)
void decoder_kernel(const float* __restrict__ input, const float* __restrict__ h0,
                    const float* __restrict__ eps,
                    const float* __restrict__ gw_ih, const float* __restrict__ gb_ih,
                    const float* __restrict__ gw_hh, const float* __restrict__ gb_hh,
                    const float* __restrict__ cw_ih, const float* __restrict__ cb_ih,
                    const float* __restrict__ cw_hh, const float* __restrict__ cb_hh,
                    const float* __restrict__ cow, const float* __restrict__ cob,
                    const float* __restrict__ fac_w, const float* __restrict__ fnorm,
                    float* __restrict__ out)
{
    __shared__ float bufA[32 * 512];   // con_input (384) -> gen_state (512) -> gs_new in place
    __shared__ float bufB[32 * 512];   // con: [state 0:256 | rh 256:512] -> cs_new in place; gen: rh (512)
    __shared__ float bufC[32 * 80];    // gen_input = [con_output 64 | ext 16]

    const int tx = threadIdx.x & 63;   // column lane
    const int ty = threadIdx.x >> 6;   // 0..7, rows r = ty + 8*rr
    const int R0 = blockIdx.x * 32;

    load_tile<256>(bufA, 0,   input + (size_t)R0 * IN_LD,       IN_LD);   // ci
    load_tile<128>(bufA, 256, h0 + (size_t)R0 * H0_LD + 976,    H0_LD);   // factor
    load_tile<256>(bufB, 0,   h0 + (size_t)R0 * H0_LD + 512,    H0_LD);   // con_state
    __syncthreads();

    float zc[4][4], xnc[4][4];

    // ================= CON GRU, phase 1: z, r, x_n; produce rh =================
#pragma unroll
    for (int g = 0; g < 4; ++g) {
        const int j = tx + 64 * g;
        float xz[4] = {0,0,0,0}, xr[4] = {0,0,0,0}, xn[4] = {0,0,0,0};
        const float4* wz = (const float4*)(cw_ih + (size_t)j * 384);
        const float4* wr = (const float4*)(cw_ih + (size_t)(j + 256) * 384);
        const float4* wn = (const float4*)(cw_ih + (size_t)(j + 512) * 384);
        for (int k4 = 0; k4 < 96; ++k4) {
            const float4 vz = wz[k4], vr = wr[k4], vn = wn[k4];
#pragma unroll
            for (int rr = 0; rr < 4; ++rr) {
                const float4 a = *(const float4*)&bufA[(ty + 8 * rr) * 512 + 4 * k4];
                fma4(xz[rr], a, vz);
                fma4(xr[rr], a, vr);
                fma4(xn[rr], a, vn);
            }
        }
        float hz[4] = {0,0,0,0}, hr[4] = {0,0,0,0};
        const float4* uz = (const float4*)(cw_hh + (size_t)j * 256);
        const float4* ur = (const float4*)(cw_hh + (size_t)(j + 256) * 256);
        for (int k4 = 0; k4 < 64; ++k4) {
            const float4 vz = uz[k4], vr = ur[k4];
#pragma unroll
            for (int rr = 0; rr < 4; ++rr) {
                const float4 a = *(const float4*)&bufB[(ty + 8 * rr) * 512 + 4 * k4];
                fma4(hz[rr], a, vz);
                fma4(hr[rr], a, vr);
            }
        }
        const float bz = cb_ih[j]       + cb_hh[j];
        const float br = cb_ih[j + 256] + cb_hh[j + 256];
        const float bn = cb_ih[j + 512];
#pragma unroll
        for (int rr = 0; rr < 4; ++rr) {
            const int r = ty + 8 * rr;
            const float z  = sigm(xz[rr] + hz[rr] + bz);
            const float rg = sigm(xr[rr] + hr[rr] + br);
            const float hold = bufB[r * 512 + j];          // con_state
            bufB[r * 512 + 256 + j] = rg * hold;           // rh -> hi half
            zc[g][rr]  = z;
            xnc[g][rr] = xn[rr] + bn;
        }
    }
    __syncthreads();

    // ================= CON GRU, phase 2: n = tanh(x_n + rh@Wn^T + b); h_new =================
#pragma unroll
    for (int g = 0; g < 4; ++g) {
        const int j = tx + 64 * g;
        float acc[4] = {0,0,0,0};
        const float4* un = (const float4*)(cw_hh + (size_t)(512 + j) * 256);
        for (int k4 = 0; k4 < 64; ++k4) {
            const float4 w = un[k4];
#pragma unroll
            for (int rr = 0; rr < 4; ++rr) {
                const float4 a = *(const float4*)&bufB[(ty + 8 * rr) * 512 + 256 + 4 * k4];
                fma4(acc[rr], a, w);
            }
        }
        const float bn = cb_hh[512 + j];
#pragma unroll
        for (int rr = 0; rr < 4; ++rr) {
            const int r = ty + 8 * rr;
            const float n = tanhf(xnc[g][rr] + acc[rr] + bn);
            const float z = zc[g][rr];
            const float hold = bufB[r * 512 + j];
            float hnew = z * hold + (1.f - z) * n;
            hnew = fminf(fmaxf(hnew, -CLIP_V), CLIP_V);
            out[(size_t)(R0 + r) * OUT_LD + 512 + j] = hnew;  // con_state'
            bufB[r * 512 + j] = hnew;                          // cs_new in place (own cell only)
        }
    }
    __syncthreads();

    // ================= CO linear + reparam; build gen_input =================
    {
        float am[4] = {0,0,0,0}, al[4] = {0,0,0,0};
        const float4* wm = (const float4*)(cow + (size_t)tx * 256);
        const float4* wl = (const float4*)(cow + (size_t)(tx + 64) * 256);
        for (int k4 = 0; k4 < 64; ++k4) {
            const float4 vm = wm[k4], vl = wl[k4];
#pragma unroll
            for (int rr = 0; rr < 4; ++rr) {
                const float4 a = *(const float4*)&bufB[(ty + 8 * rr) * 512 + 4 * k4];
                fma4(am[rr], a, vm);
                fma4(al[rr], a, vl);
            }
        }
        const float bm = cob[tx], bl = cob[tx + 64];
#pragma unroll
        for (int rr = 0; rr < 4; ++rr) {
            const int r = ty + 8 * rr;
            const size_t row = (size_t)(R0 + r);
            const float mean = am[rr] + bm;
            const float sd   = expf(0.5f * (al[rr] + bl));
            const float co_out = fmaf(sd, eps[row * 64 + tx], mean);
            out[row * OUT_LD + 768 + tx] = mean;     // co_mean'
            out[row * OUT_LD + 832 + tx] = sd;       // co_std'
            out[row * OUT_LD + 896 + tx] = co_out;   // gen_input' [0:64]
            bufC[r * 80 + tx] = co_out;
            if (tx < 16) {
                const float e = input[row * IN_LD + 256 + tx];
                bufC[r * 80 + 64 + tx] = e;
                out[row * OUT_LD + 960 + tx] = e;    // gen_input' [64:80]
            }
        }
        // bufA free since con phase 1 (2 barriers ago): stage gen_state
        load_tile<512>(bufA, 0, h0 + (size_t)R0 * H0_LD, H0_LD);
    }
    __syncthreads();

    // ================= GEN GRU, phase 1 =================
    float zg[8][4], xng[8][4];
#pragma unroll
    for (int g = 0; g < 8; ++g) {
        const int j = tx + 64 * g;
        float xz[4] = {0,0,0,0}, xr[4] = {0,0,0,0}, xn[4] = {0,0,0,0};
        const float4* wz = (const float4*)(gw_ih + (size_t)j * 80);
        const float4* wr = (const float4*)(gw_ih + (size_t)(j + 512) * 80);
        const float4* wn = (const float4*)(gw_ih + (size_t)(j + 1024) * 80);
        for (int k4 = 0; k4 < 20; ++k4) {
            const float4 vz = wz[k4], vr = wr[k4], vn = wn[k4];
#pragma unroll
            for (int rr = 0; rr < 4; ++rr) {
                const float4 a = *(const float4*)&bufC[(ty + 8 * rr) * 80 + 4 * k4];
                fma4(xz[rr], a, vz);
                fma4(xr[rr], a, vr);
                fma4(xn[rr], a, vn);
            }
        }
        float hz[4] = {0,0,0,0}, hr[4] = {0,0,0,0};
        const float4* uz = (const float4*)(gw_hh + (size_t)j * 512);
        const float4* ur = (const float4*)(gw_hh + (size_t)(j + 512) * 512);
        for (int k4 = 0; k4 < 128; ++k4) {
            const float4 vz = uz[k4], vr = ur[k4];
#pragma unroll
            for (int rr = 0; rr < 4; ++rr) {
                const float4 a = *(const float4*)&bufA[(ty + 8 * rr) * 512 + 4 * k4];
                fma4(hz[rr], a, vz);
                fma4(hr[rr], a, vr);
            }
        }
        const float bz = gb_ih[j]        + gb_hh[j];
        const float br = gb_ih[j + 512]  + gb_hh[j + 512];
        const float bn = gb_ih[j + 1024];
#pragma unroll
        for (int rr = 0; rr < 4; ++rr) {
            const int r = ty + 8 * rr;
            const float z  = sigm(xz[rr] + hz[rr] + bz);
            const float rg = sigm(xr[rr] + hr[rr] + br);
            const float hold = bufA[r * 512 + j];          // gen_state
            bufB[r * 512 + j] = rg * hold;                 // rh (cs_new dead after CO)
            zg[g][rr]  = z;
            xng[g][rr] = xn[rr] + bn;
        }
    }
    __syncthreads();

    // ================= GEN GRU, phase 2 =================
#pragma unroll
    for (int g = 0; g < 8; ++g) {
        const int j = tx + 64 * g;
        float acc[4] = {0,0,0,0};
        const float4* un = (const float4*)(gw_hh + (size_t)(1024 + j) * 512);
        for (int k4 = 0; k4 < 128; ++k4) {
            const float4 w = un[k4];
#pragma unroll
            for (int rr = 0; rr < 4; ++rr) {
                const float4 a = *(const float4*)&bufB[(ty + 8 * rr) * 512 + 4 * k4];
                fma4(acc[rr], a, w);
            }
        }
        const float bn = gb_hh[1024 + j];
#pragma unroll
        for (int rr = 0; rr < 4; ++rr) {
            const int r = ty + 8 * rr;
            const float n = tanhf(xng[g][rr] + acc[rr] + bn);
            const float z = zg[g][rr];
            const float hold = bufA[r * 512 + j];
            float hnew = z * hold + (1.f - z) * n;
            hnew = fminf(fmaxf(hnew, -CLIP_V), CLIP_V);
            out[(size_t)(R0 + r) * OUT_LD + j] = hnew;    // gen_state'
            bufA[r * 512 + j] = hnew;                      // gs_new in place (own cell only)
        }
    }
    __syncthreads();

    // ================= FACTOR readout =================
#pragma unroll
    for (int g = 0; g < 2; ++g) {
        const int j = tx + 64 * g;
        float acc[4] = {0,0,0,0};
        const float4* wf = (const float4*)(fac_w + (size_t)j * 512);
        for (int k4 = 0; k4 < 128; ++k4) {
            const float4 w = wf[k4];
#pragma unroll
            for (int rr = 0; rr < 4; ++rr) {
                const float4 a = *(const float4*)&bufA[(ty + 8 * rr) * 512 + 4 * k4];
                fma4(acc[rr], a, w);
            }
        }
        const float inv = 1.f / fnorm[j];
#pragma unroll
        for (int rr = 0; rr < 4; ++rr) {
            const int r = ty + 8 * rr;
            out[(size_t)(R0 + r) * OUT_LD + 976 + j] = acc[rr] * inv;  // factor'
        }
    }
}

extern "C" void kernel_launch(void* const* d_in, const int* in_sizes, int n_in,
                              void* d_out, int out_size, void* d_ws, size_t ws_size,
                              hipStream_t stream) {
    const float* input  = (const float*)d_in[0];
    const float* h0     = (const float*)d_in[1];
    const float* eps    = (const float*)d_in[2];
    const float* gw_ih  = (const float*)d_in[3];
    const float* gb_ih  = (const float*)d_in[4];
    const float* gw_hh  = (const float*)d_in[5];
    const float* gb_hh  = (const float*)d_in[6];
    const float* cw_ih  = (const float*)d_in[7];
    const float* cb_ih  = (const float*)d_in[8];
    const float* cw_hh  = (const float*)d_in[9];
    const float* cb_hh  = (const float*)d_in[10];
    const float* cow    = (const float*)d_in[11];
    const float* cob    = (const float*)d_in[12];
    const float* fac_w  = (const float*)d_in[13];
    float* out   = (float*)d_out;
    float* fnorm = (float*)d_ws;   // 128 floats

    fac_norm_kernel<<<128, 64, 0, stream>>>(fac_w, fnorm);

    const int nblocks = 32768 / 32;  // one block per 32 rows
    decoder_kernel<<<nblocks, 512, 0, stream>>>(
        input, h0, eps, gw_ih, gb_ih, gw_hh, gb_hh,
        cw_ih, cb_ih, cw_hh, cb_hh, cow, cob, fac_w, fnorm, out);
}

// Round 10
// 864.735 us; speedup vs baseline: 6.4312x; 6.4312x over previous
//
#include <hip/hip_runtime.h>
#include <math.h>

// ============================================================================
// Fused LFADS DecoderCell — MFMA bf16 hi/lo-split version (+ fp32 fallback).
//   con-GRU(K=640 concat)->co(256->128)+reparam->gen-GRU(K=640 concat)->factor
// Weights are pre-converted (per launch) into frag-major bf16 hi/lo tiles in
// d_ws by conv_kernel; the decoder streams them as perfectly-coalesced 32B
// granules. Activations live in LDS as separate hi/lo bf16 planes.
// h_0: [gen 0:512 | con 512:768 | mean 768:832 | std 832:896 | gin 896:976 | fac 976:1104]
// ============================================================================

#define IN_LD   272
#define H0_LD   1104
#define OUT_LD  1104
#define CLIP_V  5.0f

typedef __attribute__((ext_vector_type(8))) short bf16x8;
typedef __attribute__((ext_vector_type(4))) float f32x4;
typedef unsigned short u16;
typedef unsigned int   u32;

__device__ __forceinline__ float sigm(float x) { return 1.0f / (1.0f + expf(-x)); }

__device__ __forceinline__ u16 f2bf(float f) {            // RNE f32->bf16
    u32 u = __float_as_uint(f);
    return (u16)((u + 0x7FFF + ((u >> 16) & 1)) >> 16);
}
__device__ __forceinline__ float bf2f(u16 h) { return __uint_as_float(((u32)h) << 16); }
__device__ __forceinline__ void split2(float f, u16& hi, u16& lo) {
    hi = f2bf(f);
    lo = f2bf(f - bf2f(hi));
}

// ---------------- fac_w row norms (128 rows x 512) ----------------
__global__ void fac_norm_kernel(const float* __restrict__ fac_w,
                                float* __restrict__ norms) {
    const int j = blockIdx.x;
    const int l = threadIdx.x;
    float s = 0.f;
#pragma unroll
    for (int k = 0; k < 8; ++k) {
        const float v = fac_w[j * 512 + l + 64 * k];
        s = fmaf(v, v, s);
    }
#pragma unroll
    for (int off = 32; off > 0; off >>= 1) s += __shfl_xor(s, off);
    if (l == 0) norms[j] = fmaxf(sqrtf(s), 1e-12f);
}

// ---------------- weight pre-tiling: fp32 -> frag-major bf16 hi/lo ----------
// Granule t <-> (tile = t/(NK*64), ks = (t/64)%NK, lane = t&63):
//   col = tile*16 + (lane&15); k0 = ks*32 + (lane>>4)*8; elems k0..k0+7.
// Output 32B at dst+t*32: [hi bf16 x8 | lo bf16 x8].
// All K-segment boundaries (80,128,384) are multiples of 8 -> granule-uniform.
__global__ void conv_kernel(int mode, int total, int NK,
                            const float* __restrict__ A, const float* __restrict__ B,
                            const float* __restrict__ norms, uint4* __restrict__ dst) {
    const int t = blockIdx.x * 256 + threadIdx.x;
    if (t >= total) return;
    const int lane = t & 63;
    const int gk = t >> 6;
    const int ks = gk % NK;
    const int tile = gk / NK;
    const int col = tile * 16 + (lane & 15);
    const int k0 = ks * 32 + ((lane >> 4) << 3);

    const float* s = nullptr;
    float sc = 1.0f;
    switch (mode) {
        case 0: s = (k0 < 384) ? A + (size_t)col * 384 + k0
                               : B + (size_t)col * 256 + (k0 - 384); break;          // conZR
        case 1: s = (k0 < 384) ? A + (size_t)(512 + col) * 384 + k0
                               : B + (size_t)(512 + col) * 256 + (k0 - 384); break;  // conN
        case 2: s = A + (size_t)col * 256 + k0; break;                               // co
        case 3: s = (k0 < 80) ? A + (size_t)col * 80 + k0
                              : ((k0 < 128) ? nullptr
                                            : B + (size_t)col * 512 + (k0 - 128)); break;        // genZR
        case 4: s = (k0 < 80) ? A + (size_t)(1024 + col) * 80 + k0
                              : ((k0 < 128) ? nullptr
                                            : B + (size_t)(1024 + col) * 512 + (k0 - 128)); break; // genN (hh n-gate rows 1024..1535)
        case 5: s = A + (size_t)col * 512 + k0; sc = 1.0f / norms[col]; break;       // fac (norm folded)
    }
    u32 hw[4], lw[4];
#pragma unroll
    for (int p = 0; p < 4; ++p) {
        float v0 = s ? s[2 * p]     * sc : 0.f;
        float v1 = s ? s[2 * p + 1] * sc : 0.f;
        u16 h0, l0, h1, l1;
        split2(v0, h0, l0); split2(v1, h1, l1);
        hw[p] = (u32)h0 | ((u32)h1 << 16);
        lw[p] = (u32)l0 | ((u32)l1 << 16);
    }
    dst[(size_t)t * 2]     = make_uint4(hw[0], hw[1], hw[2], hw[3]);
    dst[(size_t)t * 2 + 1] = make_uint4(lw[0], lw[1], lw[2], lw[3]);
}

// ---------------- generic MFMA GEMM over LDS segments ----------------
struct Seg { int hi, lo, col0, st, nc; };   // short-offsets of hi/lo planes

template<int NT, int NSEG>
__device__ __forceinline__ void run_gemm(u16* sh, const Seg (&segs)[NSEG],
                                         const uint4* __restrict__ wb, int NK,
                                         int w, int l, f32x4 acc[NT][2]) {
    int kc = 0;
#pragma unroll
    for (int s = 0; s < NSEG; ++s) {
        for (int c = 0; c < segs[s].nc; ++c, ++kc) {
            bf16x8 ah[2][2], al[2][2];       // [kstep][mtile]
#pragma unroll
            for (int ks = 0; ks < 2; ++ks)
#pragma unroll
                for (int m = 0; m < 2; ++m) {
                    const int o = (m * 16 + (l & 15)) * segs[s].st
                                  + segs[s].col0 + c * 64 + ks * 32 + ((l >> 4) << 3);
                    ah[ks][m] = *(const bf16x8*)&sh[segs[s].hi + o];
                    al[ks][m] = *(const bf16x8*)&sh[segs[s].lo + o];
                }
#pragma unroll
            for (int t = 0; t < NT; ++t) {
#pragma unroll
                for (int ks = 0; ks < 2; ++ks) {
                    const uint4* wp = wb + ((((size_t)(w + 8 * t) * NK + kc * 2 + ks) * 64 + l) * 2);
                    const bf16x8 bh = *(const bf16x8*)(wp);
                    const bf16x8 bl = *(const bf16x8*)(wp + 1);
#pragma unroll
                    for (int m = 0; m < 2; ++m) {
                        acc[t][m] = __builtin_amdgcn_mfma_f32_16x16x32_bf16(ah[ks][m], bh, acc[t][m], 0, 0, 0);
                        acc[t][m] = __builtin_amdgcn_mfma_f32_16x16x32_bf16(ah[ks][m], bl, acc[t][m], 0, 0, 0);
                        acc[t][m] = __builtin_amdgcn_mfma_f32_16x16x32_bf16(al[ks][m], bh, acc[t][m], 0, 0, 0);
                    }
                }
            }
        }
    }
}

// LDS arena layout (in shorts). Planes: X/H stride 520, R2 stride 136.
#define XH 0
#define XL 16640
#define HH 33280
#define HL 49920
#define R2H 66560
#define R2L 70912
#define ARENA 75264   // 150528 B

__device__ __forceinline__ void store4(u16* sh, int offH, int offL, float4 v) {
    u16 h0, l0, h1, l1, h2, l2, h3, l3;
    split2(v.x, h0, l0); split2(v.y, h1, l1);
    split2(v.z, h2, l2); split2(v.w, h3, l3);
    uint2 ph, pl;
    ph.x = (u32)h0 | ((u32)h1 << 16); ph.y = (u32)h2 | ((u32)h3 << 16);
    pl.x = (u32)l0 | ((u32)l1 << 16); pl.y = (u32)l2 | ((u32)l3 << 16);
    *(uint2*)&sh[offH] = ph;
    *(uint2*)&sh[offL] = pl;
}

__global__ __launch_bounds__(512, 2)
void decoder_mfma(const float* __restrict__ input, const float* __restrict__ h0,
                  const float* __restrict__ eps,
                  const float* __restrict__ cb_ih, const float* __restrict__ cb_hh,
                  const float* __restrict__ gb_ih, const float* __restrict__ gb_hh,
                  const float* __restrict__ cob,
                  const uint4* __restrict__ wConZR, const uint4* __restrict__ wConN,
                  const uint4* __restrict__ wCo,    const uint4* __restrict__ wGenZR,
                  const uint4* __restrict__ wGenN,  const uint4* __restrict__ wFac,
                  float* __restrict__ out) {
    __shared__ u16 sh[ARENA];

    const int tid = threadIdx.x;
    const int w = tid >> 6;          // wave 0..7
    const int l = tid & 63;
    const int lq = l >> 4;           // row-quarter
    const int lc = l & 15;           // col-within-tile
    const int R0 = blockIdx.x * 32;

    // ---- S0: stage con_input [ci|factor] -> X planes; con_state -> H planes
#pragma unroll
    for (int i = 0; i < 10; ++i) {
        const int g = tid + 512 * i;          // 5120 granules
        const int r = g / 160;
        const int gc = g - r * 160;
        if (gc < 96) {
            const int c4 = gc * 4;
            const float4 v = (c4 < 256)
                ? *(const float4*)(input + (size_t)(R0 + r) * IN_LD + c4)
                : *(const float4*)(h0 + (size_t)(R0 + r) * H0_LD + 976 + (c4 - 256));
            store4(sh, XH + r * 520 + c4, XL + r * 520 + c4, v);
        } else {
            const int c4 = (gc - 96) * 4;
            const float4 v = *(const float4*)(h0 + (size_t)(R0 + r) * H0_LD + 512 + c4);
            store4(sh, HH + r * 520 + c4, HL + r * 520 + c4, v);
        }
    }
    __syncthreads();

    // ---- conZR GEMM: A=[X 0:384 | H 0:256], K=640, N=512
    float zhc[2][2][4], omzc[2][2][4];
    {
        const Seg segs[2] = { {XH, XL, 0, 520, 6}, {HH, HL, 0, 520, 4} };
        f32x4 acc[4][2] = {};
        run_gemm<4, 2>(sh, segs, wConZR, 20, w, l, acc);
        // glue1: z,r -> rh into H[256:512]; keep zh, 1-z
#pragma unroll
        for (int t2 = 0; t2 < 2; ++t2) {
            const int col = (w + 8 * t2) * 16 + lc;            // hidden idx 0..255
            const float bz = cb_ih[col] + cb_hh[col];
            const float br = cb_ih[256 + col] + cb_hh[256 + col];
#pragma unroll
            for (int m = 0; m < 2; ++m)
#pragma unroll
                for (int q = 0; q < 4; ++q) {
                    const int row = m * 16 + lq * 4 + q;
                    const float z = sigm(acc[t2][m][q] + bz);
                    const float r = sigm(acc[t2 + 2][m][q] + br);
                    const float h = bf2f(sh[HH + row * 520 + col]) + bf2f(sh[HL + row * 520 + col]);
                    u16 rh_h, rh_l; split2(r * h, rh_h, rh_l);
                    sh[HH + row * 520 + 256 + col] = rh_h;
                    sh[HL + row * 520 + 256 + col] = rh_l;
                    zhc[t2][m][q]  = z * h;
                    omzc[t2][m][q] = 1.f - z;
                }
        }
    }
    __syncthreads();

    // ---- conN GEMM: A=[X 0:384 | H 256:512], N=256
    {
        const Seg segs[2] = { {XH, XL, 0, 520, 6}, {HH, HL, 256, 520, 4} };
        f32x4 acc[2][2] = {};
        run_gemm<2, 2>(sh, segs, wConN, 20, w, l, acc);
        // glue2: cs_new -> out[512:768] and in-place H[0:256] planes
#pragma unroll
        for (int t = 0; t < 2; ++t) {
            const int col = (w + 8 * t) * 16 + lc;
            const float bn = cb_ih[512 + col] + cb_hh[512 + col];
#pragma unroll
            for (int m = 0; m < 2; ++m)
#pragma unroll
                for (int q = 0; q < 4; ++q) {
                    const int row = m * 16 + lq * 4 + q;
                    const float n = tanhf(acc[t][m][q] + bn);
                    float hnew = zhc[t][m][q] + omzc[t][m][q] * n;
                    hnew = fminf(fmaxf(hnew, -CLIP_V), CLIP_V);
                    out[(size_t)(R0 + row) * OUT_LD + 512 + col] = hnew;
                    u16 hh2, ll2; split2(hnew, hh2, ll2);
                    sh[HH + row * 520 + col] = hh2;
                    sh[HL + row * 520 + col] = ll2;
                }
        }
    }
    __syncthreads();

    // ---- co GEMM: A = cs_new (H 0:256), N=128 -> coParams in R2 (f32)
    {
        const Seg segs[1] = { {HH, HL, 0, 520, 4} };
        f32x4 acc[1][2] = {};
        run_gemm<1, 1>(sh, segs, wCo, 8, w, l, acc);
        float* cp = (float*)&sh[R2H];
        const int col = w * 16 + lc;
        const float bc = cob[col];
#pragma unroll
        for (int m = 0; m < 2; ++m)
#pragma unroll
            for (int q = 0; q < 4; ++q)
                cp[(m * 16 + lq * 4 + q) * 128 + col] = acc[0][m][q] + bc;
    }
    __syncthreads();

    // ---- glue3b (elementwise co/reparam, gin build) + stage gen_state
    {
        const float* cp = (const float*)&sh[R2H];
#pragma unroll
        for (int i = 0; i < 4; ++i) {               // 2048 co elements
            const int idx = tid + 512 * i;
            const int r = idx >> 6;
            const int c = idx & 63;
            const float mean = cp[r * 128 + c];
            const float lv   = cp[r * 128 + 64 + c];
            const float sd = expf(0.5f * lv);
            const size_t gr = (size_t)(R0 + r);
            const float co = fmaf(sd, eps[gr * 64 + c], mean);
            out[gr * OUT_LD + 768 + c] = mean;
            out[gr * OUT_LD + 832 + c] = sd;
            out[gr * OUT_LD + 896 + c] = co;
            u16 hh2, ll2; split2(co, hh2, ll2);
            sh[XH + r * 520 + c] = hh2;
            sh[XL + r * 520 + c] = ll2;
        }
        {                                            // ext 16 cols
            const int r = tid >> 4, c = tid & 15;
            const float e = input[(size_t)(R0 + r) * IN_LD + 256 + c];
            out[(size_t)(R0 + r) * OUT_LD + 960 + c] = e;
            u16 hh2, ll2; split2(e, hh2, ll2);
            sh[XH + r * 520 + 64 + c] = hh2;
            sh[XL + r * 520 + 64 + c] = ll2;
        }
#pragma unroll
        for (int i = 0; i < 3; ++i) {                // zero-pad gin cols 80..127
            const int idx = tid + 512 * i;
            const int r = idx / 48;
            const int c = 80 + (idx - r * 48);
            sh[XH + r * 520 + c] = 0;
            sh[XL + r * 520 + c] = 0;
        }
#pragma unroll
        for (int i = 0; i < 8; ++i) {                // gen_state -> H planes
            const int g = tid + 512 * i;             // 4096 granules
            const int r = g >> 7;
            const int c4 = (g & 127) * 4;
            const float4 v = *(const float4*)(h0 + (size_t)(R0 + r) * H0_LD + c4);
            store4(sh, HH + r * 520 + c4, HL + r * 520 + c4, v);
        }
    }
    __syncthreads();

    // ---- genZR GEMM: A=[X 0:128 (gin) | H 0:512], K=640, N=1024
    float zhg[4][2][4], omzg[4][2][4];
    {
        const Seg segs[2] = { {XH, XL, 0, 520, 2}, {HH, HL, 0, 520, 8} };
        f32x4 acc[8][2] = {};
        run_gemm<8, 2>(sh, segs, wGenZR, 20, w, l, acc);
        // glue4: rh -> X[128:512] + R2[0:128]; keep zh, 1-z
#pragma unroll
        for (int t4 = 0; t4 < 4; ++t4) {
            const int col = (w + 8 * t4) * 16 + lc;            // hidden idx 0..511
            const float bz = gb_ih[col] + gb_hh[col];
            const float br = gb_ih[512 + col] + gb_hh[512 + col];
#pragma unroll
            for (int m = 0; m < 2; ++m)
#pragma unroll
                for (int q = 0; q < 4; ++q) {
                    const int row = m * 16 + lq * 4 + q;
                    const float z = sigm(acc[t4][m][q] + bz);
                    const float r = sigm(acc[t4 + 4][m][q] + br);
                    const float h = bf2f(sh[HH + row * 520 + col]) + bf2f(sh[HL + row * 520 + col]);
                    u16 rh_h, rh_l; split2(r * h, rh_h, rh_l);
                    if (col < 384) {
                        sh[XH + row * 520 + 128 + col] = rh_h;
                        sh[XL + row * 520 + 128 + col] = rh_l;
                    } else {
                        sh[R2H + row * 136 + (col - 384)] = rh_h;
                        sh[R2L + row * 136 + (col - 384)] = rh_l;
                    }
                    zhg[t4][m][q]  = z * h;
                    omzg[t4][m][q] = 1.f - z;
                }
        }
    }
    __syncthreads();

    // ---- genN GEMM: A=[X 0:128 (gin) | X 128:512 (rh a) | R2 0:128 (rh b)], N=512
    {
        const Seg segs[3] = { {XH, XL, 0, 520, 2}, {XH, XL, 128, 520, 6}, {R2H, R2L, 0, 136, 2} };
        f32x4 acc[4][2] = {};
        run_gemm<4, 3>(sh, segs, wGenN, 20, w, l, acc);
        // glue5: gs_new -> out[0:512] and in-place H planes
#pragma unroll
        for (int t = 0; t < 4; ++t) {
            const int col = (w + 8 * t) * 16 + lc;
            const float bn = gb_ih[1024 + col] + gb_hh[1024 + col];
#pragma unroll
            for (int m = 0; m < 2; ++m)
#pragma unroll
                for (int q = 0; q < 4; ++q) {
                    const int row = m * 16 + lq * 4 + q;
                    const float n = tanhf(acc[t][m][q] + bn);
                    float hnew = zhg[t][m][q] + omzg[t][m][q] * n;
                    hnew = fminf(fmaxf(hnew, -CLIP_V), CLIP_V);
                    out[(size_t)(R0 + row) * OUT_LD + col] = hnew;
                    u16 hh2, ll2; split2(hnew, hh2, ll2);
                    sh[HH + row * 520 + col] = hh2;
                    sh[HL + row * 520 + col] = ll2;
                }
        }
    }
    __syncthreads();

    // ---- fac GEMM: A = gs_new (H 0:512), N=128 (norm pre-folded)
    {
        const Seg segs[1] = { {HH, HL, 0, 520, 8} };
        f32x4 acc[1][2] = {};
        run_gemm<1, 1>(sh, segs, wFac, 16, w, l, acc);
        const int col = w * 16 + lc;
#pragma unroll
        for (int m = 0; m < 2; ++m)
#pragma unroll
            for (int q = 0; q < 4; ++q) {
                const int row = m * 16 + lq * 4 + q;
                out[(size_t)(R0 + row) * OUT_LD + 976 + col] = acc[0][m][q];
            }
    }
}

// ============================================================================
// fp32 fallback (round-8 kernel, known-good) — used only if ws_size too small.
// ============================================================================
__device__ __forceinline__ void fma4(float& acc, const float4 a, const float4 b) {
    acc = fmaf(a.x, b.x, acc); acc = fmaf(a.y, b.y, acc);
    acc = fmaf(a.z, b.z, acc); acc = fmaf(a.w, b.w, acc);
}
template<int COLS>
__device__ __forceinline__ void load_tile(float* __restrict__ dst, int dst_col0,
                                          const float* __restrict__ src, int src_ld) {
    constexpr int C4 = COLS / 4;
    constexpr int TOT = 32 * C4;
    for (int idx = threadIdx.x; idx < TOT; idx += 512) {
        const int r = idx / C4;
        const int c = idx - r * C4;
        const float4 v = *(const float4*)(src + (size_t)r * src_ld + c * 4);
        *(float4*)(dst + r * 512 + dst_col0 + c * 4) = v;
    }
}
__global__ __launch_bounds__(512, 2)
void decoder_fp32(const float* __restrict__ input, const float* __restrict__ h0,
                  const float* __restrict__ eps,
                  const float* __restrict__ gw_ih, const float* __restrict__ gb_ih,
                  const float* __restrict__ gw_hh, const float* __restrict__ gb_hh,
                  const float* __restrict__ cw_ih, const float* __restrict__ cb_ih,
                  const float* __restrict__ cw_hh, const float* __restrict__ cb_hh,
                  const float* __restrict__ cow, const float* __restrict__ cob,
                  const float* __restrict__ fac_w, const float* __restrict__ fnorm,
                  float* __restrict__ out) {
    __shared__ float bufA[32 * 512];
    __shared__ float bufB[32 * 512];
    __shared__ float bufC[32 * 80];
    const int tx = threadIdx.x & 63;
    const int ty = threadIdx.x >> 6;
    const int R0 = blockIdx.x * 32;
    load_tile<256>(bufA, 0,   input + (size_t)R0 * IN_LD,    IN_LD);
    load_tile<128>(bufA, 256, h0 + (size_t)R0 * H0_LD + 976, H0_LD);
    load_tile<256>(bufB, 0,   h0 + (size_t)R0 * H0_LD + 512, H0_LD);
    __syncthreads();
    float zc[4][4], xnc[4][4];
#pragma unroll
    for (int g = 0; g < 4; ++g) {
        const int j = tx + 64 * g;
        float xz[4] = {0,0,0,0}, xr[4] = {0,0,0,0}, xn[4] = {0,0,0,0};
        const float4* wz = (const float4*)(cw_ih + (size_t)j * 384);
        const float4* wr = (const float4*)(cw_ih + (size_t)(j + 256) * 384);
        const float4* wn = (const float4*)(cw_ih + (size_t)(j + 512) * 384);
        for (int k4 = 0; k4 < 96; ++k4) {
            const float4 vz = wz[k4], vr = wr[k4], vn = wn[k4];
#pragma unroll
            for (int rr = 0; rr < 4; ++rr) {
                const float4 a = *(const float4*)&bufA[(ty + 8 * rr) * 512 + 4 * k4];
                fma4(xz[rr], a, vz); fma4(xr[rr], a, vr); fma4(xn[rr], a, vn);
            }
        }
        float hz[4] = {0,0,0,0}, hr[4] = {0,0,0,0};
        const float4* uz = (const float4*)(cw_hh + (size_t)j * 256);
        const float4* ur = (const float4*)(cw_hh + (size_t)(j + 256) * 256);
        for (int k4 = 0; k4 < 64; ++k4) {
            const float4 vz = uz[k4], vr = ur[k4];
#pragma unroll
            for (int rr = 0; rr < 4; ++rr) {
                const float4 a = *(const float4*)&bufB[(ty + 8 * rr) * 512 + 4 * k4];
                fma4(hz[rr], a, vz); fma4(hr[rr], a, vr);
            }
        }
        const float bz = cb_ih[j] + cb_hh[j];
        const float br = cb_ih[j + 256] + cb_hh[j + 256];
        const float bn = cb_ih[j + 512];
#pragma unroll
        for (int rr = 0; rr < 4; ++rr) {
            const int r = ty + 8 * rr;
            const float z  = sigm(xz[rr] + hz[rr] + bz);
            const float rg = sigm(xr[rr] + hr[rr] + br);
            const float hold = bufB[r * 512 + j];
            bufB[r * 512 + 256 + j] = rg * hold;
            zc[g][rr] = z; xnc[g][rr] = xn[rr] + bn;
        }
    }
    __syncthreads();
#pragma unroll
    for (int g = 0; g < 4; ++g) {
        const int j = tx + 64 * g;
        float acc[4] = {0,0,0,0};
        const float4* un = (const float4*)(cw_hh + (size_t)(512 + j) * 256);
        for (int k4 = 0; k4 < 64; ++k4) {
            const float4 ww = un[k4];
#pragma unroll
            for (int rr = 0; rr < 4; ++rr) {
                const float4 a = *(const float4*)&bufB[(ty + 8 * rr) * 512 + 256 + 4 * k4];
                fma4(acc[rr], a, ww);
            }
        }
        const float bn = cb_hh[512 + j];
#pragma unroll
        for (int rr = 0; rr < 4; ++rr) {
            const int r = ty + 8 * rr;
            const float n = tanhf(xnc[g][rr] + acc[rr] + bn);
            const float z = zc[g][rr];
            const float hold = bufB[r * 512 + j];
            float hnew = z * hold + (1.f - z) * n;
            hnew = fminf(fmaxf(hnew, -CLIP_V), CLIP_V);
            out[(size_t)(R0 + r) * OUT_LD + 512 + j] = hnew;
            bufB[r * 512 + j] = hnew;
        }
    }
    __syncthreads();
    {
        float am[4] = {0,0,0,0}, al[4] = {0,0,0,0};
        const float4* wm = (const float4*)(cow + (size_t)tx * 256);
        const float4* wl = (const float4*)(cow + (size_t)(tx + 64) * 256);
        for (int k4 = 0; k4 < 64; ++k4) {
            const float4 vm = wm[k4], vl = wl[k4];
#pragma unroll
            for (int rr = 0; rr < 4; ++rr) {
                const float4 a = *(const float4*)&bufB[(ty + 8 * rr) * 512 + 4 * k4];
                fma4(am[rr], a, vm); fma4(al[rr], a, vl);
            }
        }
        const float bm = cob[tx], bl = cob[tx + 64];
#pragma unroll
        for (int rr = 0; rr < 4; ++rr) {
            const int r = ty + 8 * rr;
            const size_t row = (size_t)(R0 + r);
            const float mean = am[rr] + bm;
            const float sd   = expf(0.5f * (al[rr] + bl));
            const float co_out = fmaf(sd, eps[row * 64 + tx], mean);
            out[row * OUT_LD + 768 + tx] = mean;
            out[row * OUT_LD + 832 + tx] = sd;
            out[row * OUT_LD + 896 + tx] = co_out;
            bufC[r * 80 + tx] = co_out;
            if (tx < 16) {
                const float e = input[row * IN_LD + 256 + tx];
                bufC[r * 80 + 64 + tx] = e;
                out[row * OUT_LD + 960 + tx] = e;
            }
        }
        load_tile<512>(bufA, 0, h0 + (size_t)R0 * H0_LD, H0_LD);
    }
    __syncthreads();
    float zg[8][4], xng[8][4];
#pragma unroll
    for (int g = 0; g < 8; ++g) {
        const int j = tx + 64 * g;
        float xz[4] = {0,0,0,0}, xr[4] = {0,0,0,0}, xn[4] = {0,0,0,0};
        const float4* wz = (const float4*)(gw_ih + (size_t)j * 80);
        const float4* wr = (const float4*)(gw_ih + (size_t)(j + 512) * 80);
        const float4* wn = (const float4*)(gw_ih + (size_t)(j + 1024) * 80);
        for (int k4 = 0; k4 < 20; ++k4) {
            const float4 vz = wz[k4], vr = wr[k4], vn = wn[k4];
#pragma unroll
            for (int rr = 0; rr < 4; ++rr) {
                const float4 a = *(const float4*)&bufC[(ty + 8 * rr) * 80 + 4 * k4];
                fma4(xz[rr], a, vz); fma4(xr[rr], a, vr); fma4(xn[rr], a, vn);
            }
        }
        float hz[4] = {0,0,0,0}, hr[4] = {0,0,0,0};
        const float4* uz = (const float4*)(gw_hh + (size_t)j * 512);
        const float4* ur = (const float4*)(gw_hh + (size_t)(j + 512) * 512);
        for (int k4 = 0; k4 < 128; ++k4) {
            const float4 vz = uz[k4], vr = ur[k4];
#pragma unroll
            for (int rr = 0; rr < 4; ++rr) {
                const float4 a = *(const float4*)&bufA[(ty + 8 * rr) * 512 + 4 * k4];
                fma4(hz[rr], a, vz); fma4(hr[rr], a, vr);
            }
        }
        const float bz = gb_ih[j] + gb_hh[j];
        const float br = gb_ih[j + 512] + gb_hh[j + 512];
        const float bn = gb_ih[j + 1024];
#pragma unroll
        for (int rr = 0; rr < 4; ++rr) {
            const int r = ty + 8 * rr;
            const float z  = sigm(xz[rr] + hz[rr] + bz);
            const float rg = sigm(xr[rr] + hr[rr] + br);
            const float hold = bufA[r * 512 + j];
            bufB[r * 512 + j] = rg * hold;
            zg[g][rr] = z; xng[g][rr] = xn[rr] + bn;
        }
    }
    __syncthreads();
#pragma unroll
    for (int g = 0; g < 8; ++g) {
        const int j = tx + 64 * g;
        float acc[4] = {0,0,0,0};
        const float4* un = (const float4*)(gw_hh + (size_t)(1024 + j) * 512);
        for (int k4 = 0; k4 < 128; ++k4) {
            const float4 ww = un[k4];
#pragma unroll
            for (int rr = 0; rr < 4; ++rr) {
                const float4 a = *(const float4*)&bufB[(ty + 8 * rr) * 512 + 4 * k4];
                fma4(acc[rr], a, ww);
            }
        }
        const float bn = gb_hh[1024 + j];
#pragma unroll
        for (int rr = 0; rr < 4; ++rr) {
            const int r = ty + 8 * rr;
            const float n = tanhf(xng[g][rr] + acc[rr] + bn);
            const float z = zg[g][rr];
            const float hold = bufA[r * 512 + j];
            float hnew = z * hold + (1.f - z) * n;
            hnew = fminf(fmaxf(hnew, -CLIP_V), CLIP_V);
            out[(size_t)(R0 + r) * OUT_LD + j] = hnew;
            bufA[r * 512 + j] = hnew;
        }
    }
    __syncthreads();
#pragma unroll
    for (int g = 0; g < 2; ++g) {
        const int j = tx + 64 * g;
        float acc[4] = {0,0,0,0};
        const float4* wf = (const float4*)(fac_w + (size_t)j * 512);
        for (int k4 = 0; k4 < 128; ++k4) {
            const float4 ww = wf[k4];
#pragma unroll
            for (int rr = 0; rr < 4; ++rr) {
                const float4 a = *(const float4*)&bufA[(ty + 8 * rr) * 512 + 4 * k4];
                fma4(acc[rr], a, ww);
            }
        }
        const float inv = 1.f / fnorm[j];
#pragma unroll
        for (int rr = 0; rr < 4; ++rr) {
            const int r = ty + 8 * rr;
            out[(size_t)(R0 + r) * OUT_LD + 976 + j] = acc[rr] * inv;
        }
    }
}

// ============================================================================
extern "C" void kernel_launch(void* const* d_in, const int* in_sizes, int n_in,
                              void* d_out, int out_size, void* d_ws, size_t ws_size,
                              hipStream_t stream) {
    const float* input  = (const float*)d_in[0];
    const float* h0     = (const float*)d_in[1];
    const float* eps    = (const float*)d_in[2];
    const float* gw_ih  = (const float*)d_in[3];
    const float* gb_ih  = (const float*)d_in[4];
    const float* gw_hh  = (const float*)d_in[5];
    const float* gb_hh  = (const float*)d_in[6];
    const float* cw_ih  = (const float*)d_in[7];
    const float* cb_ih  = (const float*)d_in[8];
    const float* cw_hh  = (const float*)d_in[9];
    const float* cb_hh  = (const float*)d_in[10];
    const float* cow    = (const float*)d_in[11];
    const float* cob    = (const float*)d_in[12];
    const float* fac_w  = (const float*)d_in[13];
    float* out = (float*)d_out;

    // ws layout (bytes)
    const size_t oConZR = 0;
    const size_t oConN  = 1310720;   // 512*640*4
    const size_t oCo    = 1966080;   // + 256*640*4
    const size_t oGenZR = 2097152;   // + 128*256*4
    const size_t oGenN  = 4718592;   // + 1024*640*4
    const size_t oFac   = 6029312;   // + 512*640*4
    const size_t oNorm  = 6291456;   // + 128*512*4
    const size_t NEED   = 6291968;   // + 128*4

    if (ws_size >= NEED) {
        char* ws = (char*)d_ws;
        float* norms = (float*)(ws + oNorm);
        fac_norm_kernel<<<128, 64, 0, stream>>>(fac_w, norms);
        conv_kernel<<<160, 256, 0, stream>>>(0, 40960, 20, cw_ih, cw_hh, nullptr, (uint4*)(ws + oConZR));
        conv_kernel<<< 80, 256, 0, stream>>>(1, 20480, 20, cw_ih, cw_hh, nullptr, (uint4*)(ws + oConN));
        conv_kernel<<< 16, 256, 0, stream>>>(2,  4096,  8, cow,   nullptr, nullptr, (uint4*)(ws + oCo));
        conv_kernel<<<320, 256, 0, stream>>>(3, 81920, 20, gw_ih, gw_hh, nullptr, (uint4*)(ws + oGenZR));
        conv_kernel<<<160, 256, 0, stream>>>(4, 40960, 20, gw_ih, gw_hh, nullptr, (uint4*)(ws + oGenN));
        conv_kernel<<< 32, 256, 0, stream>>>(5,  8192, 16, fac_w, nullptr, norms,  (uint4*)(ws + oFac));
        decoder_mfma<<<1024, 512, 0, stream>>>(
            input, h0, eps, cb_ih, cb_hh, gb_ih, gb_hh, cob,
            (const uint4*)(ws + oConZR), (const uint4*)(ws + oConN),
            (const uint4*)(ws + oCo),    (const uint4*)(ws + oGenZR),
            (const uint4*)(ws + oGenN),  (const uint4*)(ws + oFac), out);
    } else {
        float* fnorm = (float*)d_ws;   // 128 floats
        fac_norm_kernel<<<128, 64, 0, stream>>>(fac_w, fnorm);
        decoder_fp32<<<1024, 512, 0, stream>>>(
            input, h0, eps, gw_ih, gb_ih, gw_hh, gb_hh,
            cw_ih, cb_ih, cw_hh, cb_hh, cow, cob, fac_w, fnorm, out);
    }
}